// Round 11
// baseline (277.390 us; speedup 1.0000x reference)
//
#include <hip/hip_runtime.h>
#include <math.h>

#define B_    32
#define S_    4096
#define DIN_  256
#define D_    256
#define T_    256
#define NB_   4
#define K_    5
#define EPS_  1e-5f
#define ROWS_ (B_ * T_)   // 8192

#define ORS_  16          // owned rows per block
#define CR_   32          // computed rows = owned + 8 halo each side
#define BR_   36          // buf0 rows = CR_ + 2 conv-pad rows each side
#define SEGS_ 16          // T_/ORS_
#define ASTR  264         // bf16 row stride in shorts (528 B, 16B-aligned)
#define HSTR  264         // h_lds row stride in floats (1056 B, 16B-aligned)

typedef short  shortx8  __attribute__((ext_vector_type(8)));
typedef float  floatx4  __attribute__((ext_vector_type(4)));

__device__ __forceinline__ unsigned short f2bf(float f) {
    unsigned int u = __float_as_uint(f);
    u += 0x7FFFu + ((u >> 16) & 1u);
    return (unsigned short)(u >> 16);
}
__device__ __forceinline__ float bf2f(unsigned short s) {
    return __uint_as_float((unsigned int)s << 16);
}
__device__ __forceinline__ unsigned int pack2bf(float a, float b) {
    return (unsigned int)f2bf(a) | ((unsigned int)f2bf(b) << 16);
}
__device__ __forceinline__ float bf2f_lo(unsigned int u) {
    return __uint_as_float(u << 16);
}
__device__ __forceinline__ float bf2f_hi(unsigned int u) {
    return __uint_as_float(u & 0xFFFF0000u);
}

// ---------------------------------------------------------------------------
// Setup: weight convert into MFMA-FRAGMENT order (z=0..8; z=0 also emits
// lo-plane) and batch lengths (z=9).
// UNIFORM 16x16x32 fragment layout for ALL weights (in/win/wout, K=256):
// lane = ((k>>3)&3)*16 + (n&15); idx = (((n>>4)*8 + (k>>5))*64 + lane)*8 + (k&7)
// -> a wave's fragment load is base + lane*16B: one contiguous 1KB transaction
// (R10-proven: fragment order took k_fused 142 -> 90.5us).
// ---------------------------------------------------------------------------
__global__ void k_setup(const float* __restrict__ in_w, const float* __restrict__ win_w,
                        const float* __restrict__ wout_w, const unsigned int* __restrict__ mask_w,
                        unsigned short* __restrict__ wt_in, unsigned short* __restrict__ wt_in_lo,
                        unsigned short* __restrict__ wt_win,
                        unsigned short* __restrict__ wt_wout, int* __restrict__ lengths) {
    int z = blockIdx.z;
    int tid = threadIdx.x;

    if (z == 9) {
        int b = blockIdx.y * 16 + blockIdx.x;
        if (b >= B_) return;
        __shared__ int smode;
        if (tid < 64) {                           // wave 0 only: parallel detect
            unsigned int w0 = mask_w[0];
            unsigned int vi = (tid < 32) ? mask_w[tid * 1024] : 0u;
            unsigned long long anyu8 = __ballot(vi > 1u);
            if (tid == 0) smode = (w0 == 0x3F800000u) ? 2 : (anyu8 ? 1 : 0);
        }
        __syncthreads();
        int mode = smode;
        int s = 0;
        if (mode == 0) {
            const int* m = (const int*)mask_w;
            for (int i = tid; i < S_; i += 256) s += (m[(size_t)b * S_ + i] != 0);
        } else if (mode == 2) {
            const float* m = (const float*)mask_w;
            for (int i = tid; i < S_; i += 256) s += (m[(size_t)b * S_ + i] != 0.0f);
        } else {
            const unsigned char* m = (const unsigned char*)mask_w;
            for (int i = tid; i < S_; i += 256) s += (m[(size_t)b * S_ + i] != 0);
        }
        __shared__ int sm[256];
        sm[tid] = s;
        __syncthreads();
        for (int off = 128; off > 0; off >>= 1) {
            if (tid < off) sm[tid] += sm[tid + off];
            __syncthreads();
        }
        if (tid == 0) lengths[b] = sm[0];
        return;
    }

    const float* src; unsigned short* dst; int N;
    if (z == 0)      { src = in_w;                                   dst = wt_in;                                   N = D_;     }
    else if (z <= 4) { src = win_w  + (size_t)(z - 1) * D_ * 2 * D_; dst = wt_win  + (size_t)(z - 1) * 2 * D_ * D_; N = 2 * D_; }
    else             { src = wout_w + (size_t)(z - 5) * D_ * D_;     dst = wt_wout + (size_t)(z - 5) * D_ * D_;     N = D_;     }
    int bx = blockIdx.x * 32;
    int by = blockIdx.y * 32;
    if (bx >= N) return;
    __shared__ float tile[32][33];
    int tx = tid & 31, ty = tid >> 5;
#pragma unroll
    for (int i = 0; i < 32; i += 8)
        tile[ty + i][tx] = src[(size_t)(by + ty + i) * N + bx + tx];
    __syncthreads();
#pragma unroll
    for (int i = 0; i < 32; i += 8) {
        float f = tile[tx][ty + i];
        unsigned short h = f2bf(f);
        int n = bx + ty + i, k = by + tx;
        int lane = ((k >> 3) & 3) * 16 + (n & 15);
        size_t idx = ((size_t)((n >> 4) * 8 + (k >> 5)) * 64 + lane) * 8 + (k & 7);
        dst[idx] = h;
        if (z == 0) wt_in_lo[idx] = f2bf(f - bf2f(h));   // hi/lo split for in-proj
    }
}

// ---------------------------------------------------------------------------
// Fully fused network: compress + in-proj + 4 conv blocks + final LN.
// One block per (batch, 16-row segment); 32 rows computed (8 halo/side).
// R10 LESSON: fragment-ordered (coalesced) weight loads were the invariant
// ~140us term (142->90.5us). Remaining profile: MfmaUtil 15, VALUBusy 40,
// ~45% stall at 4 waves/SIMD.
// THIS ROUND: 1024 threads (16 waves), per-wave work halved, same 70KB LDS
// -> 2 blocks/CU = 2048 thr/CU = 8 waves/SIMD (max occupancy) to hide the
// stalls. launch_bounds(1024,2) caps VGPR at 64 (R6 lesson) -- per-wave
// state kept small: 16x16x32 MFMA everywhere, no weight reg-arrays; wave w
// owns gate tile w + val tile 16+w (act stays thread-local, one A-read per
// kk shared across gate/val). Math/precision identical to R10 (absmax 0.0156).
// ---------------------------------------------------------------------------
__global__ __launch_bounds__(1024, 2) void k_fused(
    const float* __restrict__ x, const int* __restrict__ lengths,
    const unsigned short* __restrict__ wt_in, const unsigned short* __restrict__ wt_in_lo,
    const float* __restrict__ in_b,
    const float* __restrict__ ln_g, const float* __restrict__ ln_b,
    const float* __restrict__ dw_w, const float* __restrict__ dw_b,
    const unsigned short* __restrict__ wt_win, const float* __restrict__ win_b,
    const unsigned short* __restrict__ wt_wout, const float* __restrict__ wout_b,
    const float* __restrict__ fn_g, const float* __restrict__ fn_b,
    float* __restrict__ out0, float* __restrict__ out1)
{
    __shared__ unsigned short buf0[BR_][ASTR];   // 19.0 KB: x-lo plane / LN out / act
    __shared__ unsigned short buf1[CR_][ASTR];   // 16.9 KB: x-hi plane / conv out
    __shared__ float h_lds[CR_][HSTR];           // 33.8 KB: resident h (fp32)

    int tid = threadIdx.x;
    int w = tid >> 6, lane = tid & 63;           // w in [0,16)
    int c16 = lane & 15, q = lane >> 4;
    int b = blockIdx.x >> 4, seg = blockIdx.x & (SEGS_ - 1);
    int t0 = seg * ORS_;
    // window row r in [0,32) corresponds to t = t0 - 8 + r

    unsigned short (*xlo)[ASTR] = (unsigned short (*)[ASTR])buf0;  // rows 0..31 alias

    int L = lengths[b];

    // ---- compress -> buf1 (hi) + buf0-alias (lo), bf16, 32 rows ----
    {
        int col = (tid & 63) * 4;
        int rg = tid >> 6;                       // [0,16)
        float Lf = (float)L;
        float hi = fmaxf(Lf - 1.0f, 0.0f);
        int L1 = max(L - 1, 0);
        const float* xb = x + (size_t)b * S_ * DIN_ + col;
#pragma unroll
        for (int e = 0; e < 2; ++e) {
            int row = rg + e * 16;
            int t = t0 - 8 + row;
            t = min(max(t, 0), T_ - 1);          // out-of-range halo rows: garbage ok, masked at LN
            float src = ((float)t + 0.5f) * (Lf * (1.0f / T_)) - 0.5f;
            src = fminf(fmaxf(src, 0.0f), hi);
            int i0 = (int)floorf(src);
            int i1 = min(i0 + 1, L1);
            float wf = src - (float)i0;
            float4 v0 = *(const float4*)&xb[(size_t)i0 * DIN_];
            float4 v1 = *(const float4*)&xb[(size_t)i1 * DIN_];
            float a0 = (1.0f - wf) * v0.x + wf * v1.x;
            float a1 = (1.0f - wf) * v0.y + wf * v1.y;
            float a2 = (1.0f - wf) * v0.z + wf * v1.z;
            float a3 = (1.0f - wf) * v0.w + wf * v1.w;
            unsigned short h0 = f2bf(a0), h1 = f2bf(a1), h2 = f2bf(a2), h3 = f2bf(a3);
            uint2 oh, ol;
            oh.x = (unsigned int)h0 | ((unsigned int)h1 << 16);
            oh.y = (unsigned int)h2 | ((unsigned int)h3 << 16);
            ol.x = (unsigned int)f2bf(a0 - bf2f(h0)) | ((unsigned int)f2bf(a1 - bf2f(h1)) << 16);
            ol.y = (unsigned int)f2bf(a2 - bf2f(h2)) | ((unsigned int)f2bf(a3 - bf2f(h3)) << 16);
            *(uint2*)&buf1[row][col] = oh;
            *(uint2*)&xlo[row][col] = ol;
        }
    }
    __syncthreads();

    // ---- in-proj GEMM (split precision): wave w -> N-tile w, mt=0,1 ----
    {
        floatx4 acc[2] = {};
#pragma unroll
        for (int kk = 0; kk < 8; ++kk) {
            size_t fo = ((size_t)(w * 8 + kk) << 9) + lane * 8;
            shortx8 bh = *(const shortx8*)(wt_in    + fo);
            shortx8 bl = *(const shortx8*)(wt_in_lo + fo);
#pragma unroll
            for (int mt = 0; mt < 2; ++mt) {
                shortx8 ah = *(const shortx8*)&buf1[mt * 16 + c16][kk * 32 + q * 8];
                shortx8 al = *(const shortx8*)&xlo[mt * 16 + c16][kk * 32 + q * 8];
                acc[mt] = __builtin_amdgcn_mfma_f32_16x16x32_bf16(ah, bh, acc[mt], 0, 0, 0);
                acc[mt] = __builtin_amdgcn_mfma_f32_16x16x32_bf16(al, bh, acc[mt], 0, 0, 0);
                acc[mt] = __builtin_amdgcn_mfma_f32_16x16x32_bf16(ah, bl, acc[mt], 0, 0, 0);
            }
        }
        float obv = in_b[w * 16 + c16];
#pragma unroll
        for (int mt = 0; mt < 2; ++mt)
#pragma unroll
            for (int r = 0; r < 4; ++r)
                h_lds[mt * 16 + q * 4 + r][w * 16 + c16] = acc[mt][r] + obv;
    }
    __syncthreads();

    // zero the conv pad rows of buf0 (rows 0,1,34,35; x-lo plane is dead now;
    // disjoint from Stage A's rows 2..33, made visible by the A->B barrier)
    if (tid < 132) {
        ((unsigned int*)buf0[0])[tid] = 0u;
        ((unsigned int*)buf0[1])[tid] = 0u;
        ((unsigned int*)buf0[BR_ - 2])[tid] = 0u;
        ((unsigned int*)buf0[BR_ - 1])[tid] = 0u;
    }

    // ---- 4 conv blocks, h resident in LDS ----
    for (int li = 0; li < NB_; ++li) {
        const float* g_i = ln_g + li * D_;
        const float* b_i = ln_b + li * D_;
        const float* dww = dw_w + (size_t)li * D_ * K_;
        const float* dwb = dw_b + li * D_;
        const unsigned short* ww = wt_win + (size_t)li * 2 * D_ * D_;
        const float* wb = win_b + (size_t)li * 2 * D_;
        const unsigned short* ow = wt_wout + (size_t)li * D_ * D_;
        const float* obp = wout_b + li * D_;

        // ---- Stage A: LN h_lds -> buf0 rows 2..33 (bf16); 2 rows/wave ----
        {
            int c4 = lane * 4;
            float4 g4 = *(const float4*)&g_i[c4];
            float4 b4 = *(const float4*)&b_i[c4];
#pragma unroll
            for (int it = 0; it < 2; ++it) {
                int r = w + it * 16;
                float4 v = *(const float4*)&h_lds[r][c4];
                float s  = v.x + v.y + v.z + v.w;
                float ss = v.x * v.x + v.y * v.y + v.z * v.z + v.w * v.w;
#pragma unroll
                for (int off = 1; off < 64; off <<= 1) {
                    s += __shfl_xor(s, off);
                    ss += __shfl_xor(ss, off);
                }
                float mu = s * (1.0f / D_);
                float rsig = rsqrtf(ss * (1.0f / D_) - mu * mu + EPS_);
                uint2 o;
                o.x = pack2bf((v.x - mu) * rsig * g4.x + b4.x,
                              (v.y - mu) * rsig * g4.y + b4.y);
                o.y = pack2bf((v.z - mu) * rsig * g4.z + b4.z,
                              (v.w - mu) * rsig * g4.w + b4.w);
                int t = t0 - 8 + r;
                if (t < 0 || t >= T_) { o.x = 0; o.y = 0; }   // zero-padded conv boundary
                *(uint2*)&buf0[r + 2][c4] = o;
            }
        }
        __syncthreads();

        // ---- Stage B: depthwise conv buf0 -> buf1 (32 rows); 2 items/thread ----
        {
            int col = (tid & 63) * 4;
            int rg = tid >> 6;
            float4 wk[K_];
#pragma unroll
            for (int k = 0; k < K_; ++k) {
                wk[k].x = dww[(col + 0) * K_ + k];
                wk[k].y = dww[(col + 1) * K_ + k];
                wk[k].z = dww[(col + 2) * K_ + k];
                wk[k].w = dww[(col + 3) * K_ + k];
            }
            float4 cb4 = *(const float4*)&dwb[col];
#pragma unroll
            for (int e = 0; e < 2; ++e) {
                int rr = rg + e * 16;
                float4 acc = cb4;
#pragma unroll
                for (int k = 0; k < K_; ++k) {
                    uint2 u = *(const uint2*)&buf0[rr + k][col];
                    acc.x += bf2f_lo(u.x) * wk[k].x;
                    acc.y += bf2f_hi(u.x) * wk[k].y;
                    acc.z += bf2f_lo(u.y) * wk[k].z;
                    acc.w += bf2f_hi(u.y) * wk[k].w;
                }
                uint2 o;
                o.x = pack2bf(acc.x, acc.y);
                o.y = pack2bf(acc.z, acc.w);
                *(uint2*)&buf1[rr][col] = o;
            }
        }
        __syncthreads();

        // ---- Stage C: win GEMM (32x512) + fused act -> buf0 rows 2..33 ----
        // Wave w: gate N-tile w (cols w*16..) and val N-tile 16+w (cols
        // 256+w*16..). One A-read per (kk,mt) feeds both MFMA chains; act is
        // thread-local (gate/val in same lane). Coalesced fragment B loads.
        {
            floatx4 accG[2] = {}, accV[2] = {};
#pragma unroll
            for (int kk = 0; kk < 8; ++kk) {
                shortx8 bg = *(const shortx8*)(ww + (((size_t)(w * 8 + kk)) << 9) + lane * 8);
                shortx8 bv = *(const shortx8*)(ww + (((size_t)((16 + w) * 8 + kk)) << 9) + lane * 8);
#pragma unroll
                for (int mt = 0; mt < 2; ++mt) {
                    shortx8 a = *(const shortx8*)&buf1[mt * 16 + c16][kk * 32 + q * 8];
                    accG[mt] = __builtin_amdgcn_mfma_f32_16x16x32_bf16(a, bg, accG[mt], 0, 0, 0);
                    accV[mt] = __builtin_amdgcn_mfma_f32_16x16x32_bf16(a, bv, accV[mt], 0, 0, 0);
                }
            }
            float bg0 = wb[w * 16 + c16];
            float bv0 = wb[256 + w * 16 + c16];
            int colw = w * 16 + c16;
#pragma unroll
            for (int mt = 0; mt < 2; ++mt)
#pragma unroll
                for (int r = 0; r < 4; ++r) {
                    float gate = accG[mt][r] + bg0;
                    float val  = accV[mt][r] + bv0;
                    float sg = 1.0f / (1.0f + __expf(-gate));
                    float u = 1.5957691216f * (val + 0.044715f * val * val * val);
                    float ge = val / (1.0f + __expf(-u));
                    buf0[2 + mt * 16 + q * 4 + r][colw] = f2bf(sg * ge);
                }
        }
        __syncthreads();

        // ---- Stage D: wout GEMM (32x256) + residual; wave w -> N-tile w ----
        {
            floatx4 acc[2] = {};
#pragma unroll
            for (int kk = 0; kk < 8; ++kk) {
                shortx8 bo = *(const shortx8*)(ow + (((size_t)(w * 8 + kk)) << 9) + lane * 8);
#pragma unroll
                for (int mt = 0; mt < 2; ++mt) {
                    shortx8 a = *(const shortx8*)&buf0[2 + mt * 16 + c16][kk * 32 + q * 8];
                    acc[mt] = __builtin_amdgcn_mfma_f32_16x16x32_bf16(a, bo, acc[mt], 0, 0, 0);
                }
            }
            float bb = obp[w * 16 + c16];
#pragma unroll
            for (int mt = 0; mt < 2; ++mt)
#pragma unroll
                for (int r = 0; r < 4; ++r) {
                    int row = mt * 16 + q * 4 + r;
                    int col = w * 16 + c16;
                    h_lds[row][col] = h_lds[row][col] + acc[mt][r] + bb;
                }
        }
        __syncthreads();
    }

    // ---- final LN on owned rows (8..23) -> out0; comp_mask -> out1 ----
    {
        int c4 = lane * 4;
        float4 g4 = *(const float4*)&fn_g[c4];
        float4 b4 = *(const float4*)&fn_b[c4];
        int r = 8 + w;                            // one row per wave, rows 8..23
        float4 v = *(const float4*)&h_lds[r][c4];
        float s  = v.x + v.y + v.z + v.w;
        float ss = v.x * v.x + v.y * v.y + v.z * v.z + v.w * v.w;
#pragma unroll
        for (int off = 1; off < 64; off <<= 1) {
            s += __shfl_xor(s, off);
            ss += __shfl_xor(ss, off);
        }
        float mu = s * (1.0f / D_);
        float rsig = rsqrtf(ss * (1.0f / D_) - mu * mu + EPS_);
        float4 o;
        o.x = (v.x - mu) * rsig * g4.x + b4.x;
        o.y = (v.y - mu) * rsig * g4.y + b4.y;
        o.z = (v.z - mu) * rsig * g4.z + b4.z;
        o.w = (v.w - mu) * rsig * g4.w + b4.w;
        *(float4*)&out0[((size_t)b * T_ + t0 + r - 8) * D_ + c4] = o;
        if (tid < ORS_) out1[(size_t)b * T_ + t0 + tid] = 1.0f;
    }
}

// ---------------------------------------------------------------------------
extern "C" void kernel_launch(void* const* d_in, const int* in_sizes, int n_in,
                              void* d_out, int out_size, void* d_ws, size_t ws_size,
                              hipStream_t stream) {
    const float* x      = (const float*)d_in[0];
    const unsigned int* mask_w = (const unsigned int*)d_in[1];
    const float* in_w   = (const float*)d_in[2];
    const float* in_b   = (const float*)d_in[3];
    const float* ln_g   = (const float*)d_in[4];
    const float* ln_b   = (const float*)d_in[5];
    const float* dw_w   = (const float*)d_in[6];
    const float* dw_b   = (const float*)d_in[7];
    const float* win_w  = (const float*)d_in[8];
    const float* win_b  = (const float*)d_in[9];
    const float* wout_w = (const float*)d_in[10];
    const float* wout_b = (const float*)d_in[11];
    const float* fn_g   = (const float*)d_in[12];
    const float* fn_b   = (const float*)d_in[13];

    char* w8 = (char*)d_ws;
    unsigned short* wt_in   = (unsigned short*)w8;                 // 128 KB
    unsigned short* wt_win  = wt_in  + (size_t)D_ * DIN_;          // 1 MB
    unsigned short* wt_wout = wt_win + (size_t)NB_ * 2 * D_ * D_;  // 512 KB
    int* lengths = (int*)(w8 + (2u << 20));                        // 128 B
    unsigned short* wt_in_lo = (unsigned short*)(w8 + (3u << 20)); // 128 KB

    float* out0 = (float*)d_out;
    float* out1 = out0 + (size_t)ROWS_ * D_;

    k_setup<<<dim3(16, 8, 10), 256, 0, stream>>>(in_w, win_w, wout_w, mask_w,
                                                 wt_in, wt_in_lo, wt_win, wt_wout, lengths);
    k_fused<<<B_ * SEGS_, 1024, 0, stream>>>(x, lengths, wt_in, wt_in_lo, in_b,
                                             ln_g, ln_b, dw_w, dw_b,
                                             wt_win, win_b, wt_wout, wout_b,
                                             fn_g, fn_b, out0, out1);
}

// Round 12
// 266.705 us; speedup vs baseline: 1.0401x; 1.0401x over previous
//
#include <hip/hip_runtime.h>
#include <math.h>

#define B_    32
#define S_    4096
#define DIN_  256
#define D_    256
#define T_    256
#define NB_   4
#define K_    5
#define EPS_  1e-5f
#define ROWS_ (B_ * T_)   // 8192

#define ORS_  16          // owned rows per block
#define CR_   32          // computed rows = owned + 8 halo each side
#define BR_   36          // buf0 rows = CR_ + 2 conv-pad rows each side
#define SEGS_ 16          // T_/ORS_
#define ASTR  264         // bf16 row stride in shorts (528 B, 16B-aligned)
#define HSTR  264         // h_lds row stride in floats (1056 B, 16B-aligned)

typedef short  shortx8  __attribute__((ext_vector_type(8)));
typedef float  floatx4  __attribute__((ext_vector_type(4)));
typedef float  floatx16 __attribute__((ext_vector_type(16)));

__device__ __forceinline__ unsigned short f2bf(float f) {
    unsigned int u = __float_as_uint(f);
    u += 0x7FFFu + ((u >> 16) & 1u);
    return (unsigned short)(u >> 16);
}
__device__ __forceinline__ float bf2f(unsigned short s) {
    return __uint_as_float((unsigned int)s << 16);
}
__device__ __forceinline__ unsigned int pack2bf(float a, float b) {
    return (unsigned int)f2bf(a) | ((unsigned int)f2bf(b) << 16);
}
__device__ __forceinline__ float bf2f_lo(unsigned int u) {
    return __uint_as_float(u << 16);
}
__device__ __forceinline__ float bf2f_hi(unsigned int u) {
    return __uint_as_float(u & 0xFFFF0000u);
}

// ---------------------------------------------------------------------------
// Setup: weight convert into MFMA-FRAGMENT order (z=0..8; z=0 also emits
// lo-plane) and batch lengths (z=9).
// Fragment order: flat = ((tile*NKK + kk)*64 + lane)*8 + j  -> a wave's
// fragment load is base + lane*16B: ONE contiguous 1KB transaction
// (R10-proven: 142 -> 90.5us).
// in-proj (16x16x32): lane = ((k>>3)&3)*16 + (n&15), kk = k>>5, NKK=8.
// win/wout (32x32x16): lane = ((k>>3)&1)*32 + (n&31), kk = k>>4, NKK=16.
// ---------------------------------------------------------------------------
__global__ void k_setup(const float* __restrict__ in_w, const float* __restrict__ win_w,
                        const float* __restrict__ wout_w, const unsigned int* __restrict__ mask_w,
                        unsigned short* __restrict__ wt_in, unsigned short* __restrict__ wt_in_lo,
                        unsigned short* __restrict__ wt_win,
                        unsigned short* __restrict__ wt_wout, int* __restrict__ lengths) {
    int z = blockIdx.z;
    int tid = threadIdx.x;

    if (z == 9) {
        int b = blockIdx.y * 16 + blockIdx.x;
        if (b >= B_) return;
        __shared__ int smode;
        if (tid < 64) {                           // wave 0 only: parallel detect
            unsigned int w0 = mask_w[0];
            unsigned int vi = (tid < 32) ? mask_w[tid * 1024] : 0u;
            unsigned long long anyu8 = __ballot(vi > 1u);
            if (tid == 0) smode = (w0 == 0x3F800000u) ? 2 : (anyu8 ? 1 : 0);
        }
        __syncthreads();
        int mode = smode;
        int s = 0;
        if (mode == 0) {
            const int* m = (const int*)mask_w;
            for (int i = tid; i < S_; i += 256) s += (m[(size_t)b * S_ + i] != 0);
        } else if (mode == 2) {
            const float* m = (const float*)mask_w;
            for (int i = tid; i < S_; i += 256) s += (m[(size_t)b * S_ + i] != 0.0f);
        } else {
            const unsigned char* m = (const unsigned char*)mask_w;
            for (int i = tid; i < S_; i += 256) s += (m[(size_t)b * S_ + i] != 0);
        }
        __shared__ int sm[256];
        sm[tid] = s;
        __syncthreads();
        for (int off = 128; off > 0; off >>= 1) {
            if (tid < off) sm[tid] += sm[tid + off];
            __syncthreads();
        }
        if (tid == 0) lengths[b] = sm[0];
        return;
    }

    const float* src; unsigned short* dst; int N;
    if (z == 0)      { src = in_w;                                   dst = wt_in;                                   N = D_;     }
    else if (z <= 4) { src = win_w  + (size_t)(z - 1) * D_ * 2 * D_; dst = wt_win  + (size_t)(z - 1) * 2 * D_ * D_; N = 2 * D_; }
    else             { src = wout_w + (size_t)(z - 5) * D_ * D_;     dst = wt_wout + (size_t)(z - 5) * D_ * D_;     N = D_;     }
    int bx = blockIdx.x * 32;
    int by = blockIdx.y * 32;
    if (bx >= N) return;
    __shared__ float tile[32][33];
    int tx = tid & 31, ty = tid >> 5;
#pragma unroll
    for (int i = 0; i < 32; i += 8)
        tile[ty + i][tx] = src[(size_t)(by + ty + i) * N + bx + tx];
    __syncthreads();
#pragma unroll
    for (int i = 0; i < 32; i += 8) {
        float f = tile[tx][ty + i];
        unsigned short h = f2bf(f);
        int n = bx + ty + i, k = by + tx;
        if (z == 0) {
            int lane = ((k >> 3) & 3) * 16 + (n & 15);
            size_t idx = ((size_t)((n >> 4) * 8 + (k >> 5)) * 64 + lane) * 8 + (k & 7);
            wt_in[idx] = h;
            wt_in_lo[idx] = f2bf(f - bf2f(h));   // hi/lo split for in-proj
        } else {
            int lane = ((k >> 3) & 1) * 32 + (n & 31);
            size_t idx = ((size_t)((n >> 5) * 16 + (k >> 4)) * 64 + lane) * 8 + (k & 7);
            dst[idx] = h;
        }
    }
}

// ---------------------------------------------------------------------------
// Fully fused network: compress + in-proj + 4 conv blocks + final LN.
// One block per (batch, 16-row segment); 32 rows computed (8 halo/side).
// 512 threads, 70KB LDS, 2 blocks/CU. R10 config (90.5us) = best measured.
// R11 LESSON: 8 waves/SIMD is SLOWER (102us) -> not TLP-starved; stall is
// stage-transition load latency (barrier vmcnt(0) drain exposes each
// stage's first weight loads to all waves at once) + dep chains.
// THIS ROUND: register prefetch across stages (survives barrier drains):
// Bg[16] (gate win-tile, 64 VGPR) issued at layer top, consumed 2 stages
// later in C; Bo[8] (half wout-tile) prefetched under C's act epilogue.
// (512,2) -> 128-VGPR cap (R6 lesson: (512,4) capped 64 and spilled).
// Act uses single rcp: val*rcp((1+e^-g)(1+e^-u)) -- 1 rcp vs 2 divides.
// ---------------------------------------------------------------------------
__global__ __launch_bounds__(512, 2) void k_fused(
    const float* __restrict__ x, const int* __restrict__ lengths,
    const unsigned short* __restrict__ wt_in, const unsigned short* __restrict__ wt_in_lo,
    const float* __restrict__ in_b,
    const float* __restrict__ ln_g, const float* __restrict__ ln_b,
    const float* __restrict__ dw_w, const float* __restrict__ dw_b,
    const unsigned short* __restrict__ wt_win, const float* __restrict__ win_b,
    const unsigned short* __restrict__ wt_wout, const float* __restrict__ wout_b,
    const float* __restrict__ fn_g, const float* __restrict__ fn_b,
    float* __restrict__ out0, float* __restrict__ out1)
{
    __shared__ unsigned short buf0[BR_][ASTR];   // 19.0 KB: x-lo plane / LN out / act
    __shared__ unsigned short buf1[CR_][ASTR];   // 16.9 KB: x-hi plane / conv out
    __shared__ float h_lds[CR_][HSTR];           // 33.8 KB: resident h (fp32)

    int tid = threadIdx.x;
    int w = tid >> 6, lane = tid & 63;
    int c16 = lane & 15, q = lane >> 4;
    int l31 = lane & 31, lh = lane >> 5;         // 32x32 fragment coords
    int b = blockIdx.x >> 4, seg = blockIdx.x & (SEGS_ - 1);
    int t0 = seg * ORS_;
    // window row r in [0,32) corresponds to t = t0 - 8 + r

    unsigned short (*xlo)[ASTR] = (unsigned short (*)[ASTR])buf0;  // rows 0..31 alias

    int L = lengths[b];

    // ---- compress -> buf1 (hi) + buf0-alias (lo), bf16, 32 rows ----
    {
        int tq = tid & 63, rg = tid >> 6;
        int col = tq * 4;
        float Lf = (float)L;
        float hi = fmaxf(Lf - 1.0f, 0.0f);
        int L1 = max(L - 1, 0);
        const float* xb = x + (size_t)b * S_ * DIN_ + col;
#pragma unroll
        for (int e = 0; e < 4; ++e) {
            int row = rg + e * 8;
            int t = t0 - 8 + row;
            t = min(max(t, 0), T_ - 1);          // out-of-range halo rows: garbage ok, masked at LN
            float src = ((float)t + 0.5f) * (Lf * (1.0f / T_)) - 0.5f;
            src = fminf(fmaxf(src, 0.0f), hi);
            int i0 = (int)floorf(src);
            int i1 = min(i0 + 1, L1);
            float wf = src - (float)i0;
            float4 v0 = *(const float4*)&xb[(size_t)i0 * DIN_];
            float4 v1 = *(const float4*)&xb[(size_t)i1 * DIN_];
            float a0 = (1.0f - wf) * v0.x + wf * v1.x;
            float a1 = (1.0f - wf) * v0.y + wf * v1.y;
            float a2 = (1.0f - wf) * v0.z + wf * v1.z;
            float a3 = (1.0f - wf) * v0.w + wf * v1.w;
            unsigned short h0 = f2bf(a0), h1 = f2bf(a1), h2 = f2bf(a2), h3 = f2bf(a3);
            uint2 oh, ol;
            oh.x = (unsigned int)h0 | ((unsigned int)h1 << 16);
            oh.y = (unsigned int)h2 | ((unsigned int)h3 << 16);
            ol.x = (unsigned int)f2bf(a0 - bf2f(h0)) | ((unsigned int)f2bf(a1 - bf2f(h1)) << 16);
            ol.y = (unsigned int)f2bf(a2 - bf2f(h2)) | ((unsigned int)f2bf(a3 - bf2f(h3)) << 16);
            *(uint2*)&buf1[row][col] = oh;
            *(uint2*)&xlo[row][col] = ol;
        }
    }
    __syncthreads();

    // ---- in-proj GEMM (split precision, fragment-ordered weights) ----
#pragma unroll
    for (int nn = 0; nn < 2; ++nn) {
        int nt = w + nn * 8;
        floatx4 acc[2] = {};
#pragma unroll
        for (int kk = 0; kk < 8; ++kk) {
            size_t fo = ((size_t)(nt * 8 + kk) << 9) + lane * 8;   // (tile*8+kk)*512 + lane*8
            shortx8 bh = *(const shortx8*)(wt_in    + fo);
            shortx8 bl = *(const shortx8*)(wt_in_lo + fo);
#pragma unroll
            for (int mt = 0; mt < 2; ++mt) {
                shortx8 ah = *(const shortx8*)&buf1[mt * 16 + c16][kk * 32 + q * 8];
                shortx8 al = *(const shortx8*)&xlo[mt * 16 + c16][kk * 32 + q * 8];
                acc[mt] = __builtin_amdgcn_mfma_f32_16x16x32_bf16(ah, bh, acc[mt], 0, 0, 0);
                acc[mt] = __builtin_amdgcn_mfma_f32_16x16x32_bf16(al, bh, acc[mt], 0, 0, 0);
                acc[mt] = __builtin_amdgcn_mfma_f32_16x16x32_bf16(ah, bl, acc[mt], 0, 0, 0);
            }
        }
        float obv = in_b[nt * 16 + c16];
#pragma unroll
        for (int mt = 0; mt < 2; ++mt)
#pragma unroll
            for (int r = 0; r < 4; ++r)
                h_lds[mt * 16 + q * 4 + r][nt * 16 + c16] = acc[mt][r] + obv;
    }
    __syncthreads();

    // zero the conv pad rows of buf0 (rows 0,1,34,35; x-lo plane is dead now;
    // disjoint from Stage A's rows 2..33, made visible by the A->B barrier)
    if (tid < 132) {
        ((unsigned int*)buf0[0])[tid] = 0u;
        ((unsigned int*)buf0[1])[tid] = 0u;
        ((unsigned int*)buf0[BR_ - 2])[tid] = 0u;
        ((unsigned int*)buf0[BR_ - 1])[tid] = 0u;
    }

    // ---- 4 conv blocks, h resident in LDS ----
    for (int li = 0; li < NB_; ++li) {
        const float* g_i = ln_g + li * D_;
        const float* b_i = ln_b + li * D_;
        const float* dww = dw_w + (size_t)li * D_ * K_;
        const float* dwb = dw_b + li * D_;
        const unsigned short* ww = wt_win + (size_t)li * 2 * D_ * D_;
        const float* wb = win_b + (size_t)li * 2 * D_;
        const unsigned short* ow = wt_wout + (size_t)li * D_ * D_;
        const float* obp = wout_b + li * D_;

        // prefetch gate win-tile into regs (64 VGPR). Loads issue here and
        // complete across Stage A/B -- register prefetch survives the
        // barrier vmcnt(0) drains (data simply lands early).
        shortx8 Bg[16];
#pragma unroll
        for (int kk = 0; kk < 16; ++kk)
            Bg[kk] = *(const shortx8*)(ww + ((size_t)(w * 16 + kk) << 9) + lane * 8);

        // ---- Stage A: LN h_lds -> buf0 rows 2..33 (bf16), zero out-of-range t ----
        {
            int c4 = lane * 4;
            float4 g4 = *(const float4*)&g_i[c4];
            float4 b4 = *(const float4*)&b_i[c4];
#pragma unroll
            for (int it = 0; it < 4; ++it) {
                int r = w + it * 8;
                float4 v = *(const float4*)&h_lds[r][c4];
                float s  = v.x + v.y + v.z + v.w;
                float ss = v.x * v.x + v.y * v.y + v.z * v.z + v.w * v.w;
#pragma unroll
                for (int off = 1; off < 64; off <<= 1) {
                    s += __shfl_xor(s, off);
                    ss += __shfl_xor(ss, off);
                }
                float mu = s * (1.0f / D_);
                float rsig = rsqrtf(ss * (1.0f / D_) - mu * mu + EPS_);
                uint2 o;
                o.x = pack2bf((v.x - mu) * rsig * g4.x + b4.x,
                              (v.y - mu) * rsig * g4.y + b4.y);
                o.y = pack2bf((v.z - mu) * rsig * g4.z + b4.z,
                              (v.w - mu) * rsig * g4.w + b4.w);
                int t = t0 - 8 + r;
                if (t < 0 || t >= T_) { o.x = 0; o.y = 0; }   // zero-padded conv boundary
                *(uint2*)&buf0[r + 2][c4] = o;
            }
        }
        __syncthreads();

        // ---- Stage B: depthwise conv buf0 -> buf1 (32 rows) ----
        {
            int tq = tid & 63, rg = tid >> 6;
            int col = tq * 4;
            float4 wk[K_];
#pragma unroll
            for (int k = 0; k < K_; ++k) {
                wk[k].x = dww[(col + 0) * K_ + k];
                wk[k].y = dww[(col + 1) * K_ + k];
                wk[k].z = dww[(col + 2) * K_ + k];
                wk[k].w = dww[(col + 3) * K_ + k];
            }
            float4 cb4 = *(const float4*)&dwb[col];
#pragma unroll
            for (int e = 0; e < 4; ++e) {
                int rr = rg + e * 8;
                float4 acc = cb4;
#pragma unroll
                for (int k = 0; k < K_; ++k) {
                    uint2 u = *(const uint2*)&buf0[rr + k][col];
                    acc.x += bf2f_lo(u.x) * wk[k].x;
                    acc.y += bf2f_hi(u.x) * wk[k].y;
                    acc.z += bf2f_lo(u.y) * wk[k].z;
                    acc.w += bf2f_hi(u.y) * wk[k].w;
                }
                uint2 o;
                o.x = pack2bf(acc.x, acc.y);
                o.y = pack2bf(acc.z, acc.w);
                *(uint2*)&buf1[rr][col] = o;
            }
        }
        __syncthreads();

        // ---- Stage C: win GEMM (32x512) via 32x32x16 MFMA + fused act ----
        // Gate weights from prefetched Bg; val weights stream inline (hidden
        // under the MFMA chain). One A-read per kk feeds both tiles.
        {
            floatx16 accG = {}, accV = {};
#pragma unroll
            for (int kk = 0; kk < 16; ++kk) {
                shortx8 a  = *(const shortx8*)&buf1[l31][kk * 16 + lh * 8];
                shortx8 bv = *(const shortx8*)(ww + ((size_t)((8 + w) * 16 + kk) << 9) + lane * 8);
                accG = __builtin_amdgcn_mfma_f32_32x32x16_bf16(a, Bg[kk], accG, 0, 0, 0);
                accV = __builtin_amdgcn_mfma_f32_32x32x16_bf16(a, bv, accV, 0, 0, 0);
            }
            // prefetch first half of wout tile (32 VGPR) under the act epilogue
            shortx8 Bo[8];
#pragma unroll
            for (int kk = 0; kk < 8; ++kk)
                Bo[kk] = *(const shortx8*)(ow + ((size_t)(w * 16 + kk) << 9) + lane * 8);
            float bg0 = wb[w * 32 + l31];
            float bv0 = wb[256 + w * 32 + l31];
#pragma unroll
            for (int r = 0; r < 16; ++r) {
                int row = (r & 3) + 8 * (r >> 2) + 4 * lh;
                float gate = accG[r] + bg0;
                float val  = accV[r] + bv0;
                float u = 1.5957691216f * (val + 0.044715f * val * val * val);
                float den = (1.0f + __expf(-gate)) * (1.0f + __expf(-u));
                buf0[2 + row][w * 32 + l31] = f2bf(val * __builtin_amdgcn_rcpf(den));
            }
            __syncthreads();

            // ---- Stage D: wout GEMM (32x256) via 32x32x16 + residual ----
            floatx16 acc = {};
#pragma unroll
            for (int kk = 0; kk < 8; ++kk) {
                shortx8 a = *(const shortx8*)&buf0[2 + l31][kk * 16 + lh * 8];
                acc = __builtin_amdgcn_mfma_f32_32x32x16_bf16(a, Bo[kk], acc, 0, 0, 0);
            }
#pragma unroll
            for (int kk = 8; kk < 16; ++kk) {
                shortx8 a  = *(const shortx8*)&buf0[2 + l31][kk * 16 + lh * 8];
                shortx8 bo = *(const shortx8*)(ow + ((size_t)(w * 16 + kk) << 9) + lane * 8);
                acc = __builtin_amdgcn_mfma_f32_32x32x16_bf16(a, bo, acc, 0, 0, 0);
            }
            float bb = obp[w * 32 + l31];
#pragma unroll
            for (int r = 0; r < 16; ++r) {
                int row = (r & 3) + 8 * (r >> 2) + 4 * lh;
                int col = w * 32 + l31;
                h_lds[row][col] = h_lds[row][col] + acc[r] + bb;
            }
        }
        __syncthreads();
    }

    // ---- final LN on owned rows (8..23) -> out0; comp_mask -> out1 ----
    {
        int c4 = lane * 4;
        float4 g4 = *(const float4*)&fn_g[c4];
        float4 b4 = *(const float4*)&fn_b[c4];
#pragma unroll
        for (int it = 0; it < 2; ++it) {
            int r = 8 + w + it * 8;
            float4 v = *(const float4*)&h_lds[r][c4];
            float s  = v.x + v.y + v.z + v.w;
            float ss = v.x * v.x + v.y * v.y + v.z * v.z + v.w * v.w;
#pragma unroll
            for (int off = 1; off < 64; off <<= 1) {
                s += __shfl_xor(s, off);
                ss += __shfl_xor(ss, off);
            }
            float mu = s * (1.0f / D_);
            float rsig = rsqrtf(ss * (1.0f / D_) - mu * mu + EPS_);
            float4 o;
            o.x = (v.x - mu) * rsig * g4.x + b4.x;
            o.y = (v.y - mu) * rsig * g4.y + b4.y;
            o.z = (v.z - mu) * rsig * g4.z + b4.z;
            o.w = (v.w - mu) * rsig * g4.w + b4.w;
            *(float4*)&out0[((size_t)b * T_ + t0 + r - 8) * D_ + c4] = o;
        }
        if (tid < ORS_) out1[(size_t)b * T_ + t0 + tid] = 1.0f;
    }
}

// ---------------------------------------------------------------------------
extern "C" void kernel_launch(void* const* d_in, const int* in_sizes, int n_in,
                              void* d_out, int out_size, void* d_ws, size_t ws_size,
                              hipStream_t stream) {
    const float* x      = (const float*)d_in[0];
    const unsigned int* mask_w = (const unsigned int*)d_in[1];
    const float* in_w   = (const float*)d_in[2];
    const float* in_b   = (const float*)d_in[3];
    const float* ln_g   = (const float*)d_in[4];
    const float* ln_b   = (const float*)d_in[5];
    const float* dw_w   = (const float*)d_in[6];
    const float* dw_b   = (const float*)d_in[7];
    const float* win_w  = (const float*)d_in[8];
    const float* win_b  = (const float*)d_in[9];
    const float* wout_w = (const float*)d_in[10];
    const float* wout_b = (const float*)d_in[11];
    const float* fn_g   = (const float*)d_in[12];
    const float* fn_b   = (const float*)d_in[13];

    char* w8 = (char*)d_ws;
    unsigned short* wt_in   = (unsigned short*)w8;                 // 128 KB
    unsigned short* wt_win  = wt_in  + (size_t)D_ * DIN_;          // 1 MB
    unsigned short* wt_wout = wt_win + (size_t)NB_ * 2 * D_ * D_;  // 512 KB
    int* lengths = (int*)(w8 + (2u << 20));                        // 128 B
    unsigned short* wt_in_lo = (unsigned short*)(w8 + (3u << 20)); // 128 KB

    float* out0 = (float*)d_out;
    float* out1 = out0 + (size_t)ROWS_ * D_;

    k_setup<<<dim3(16, 8, 10), 256, 0, stream>>>(in_w, win_w, wout_w, mask_w,
                                                 wt_in, wt_in_lo, wt_win, wt_wout, lengths);
    k_fused<<<B_ * SEGS_, 512, 0, stream>>>(x, lengths, wt_in, wt_in_lo, in_b,
                                            ln_g, ln_b, dw_w, dw_b,
                                            wt_win, win_b, wt_wout, wout_b,
                                            fn_g, fn_b, out0, out1);
}

// Round 13
// 263.990 us; speedup vs baseline: 1.0508x; 1.0103x over previous
//
#include <hip/hip_runtime.h>
#include <math.h>

#define B_    32
#define S_    4096
#define DIN_  256
#define D_    256
#define T_    256
#define NB_   4
#define K_    5
#define EPS_  1e-5f
#define ROWS_ (B_ * T_)   // 8192

#define ORS_  16          // owned rows per block
#define CR_   32          // computed rows = owned + 8 halo each side
#define BR_   36          // buf0 rows = CR_ + 2 conv-pad rows each side
#define SEGS_ 16          // T_/ORS_
#define ASTR  264         // bf16 row stride in shorts (528 B, 16B-aligned)
#define HSTR  264         // h_lds row stride in floats (1056 B, 16B-aligned)

typedef short  shortx8  __attribute__((ext_vector_type(8)));
typedef float  floatx4  __attribute__((ext_vector_type(4)));
typedef float  floatx16 __attribute__((ext_vector_type(16)));

__device__ __forceinline__ unsigned short f2bf(float f) {
    unsigned int u = __float_as_uint(f);
    u += 0x7FFFu + ((u >> 16) & 1u);
    return (unsigned short)(u >> 16);
}
__device__ __forceinline__ float bf2f(unsigned short s) {
    return __uint_as_float((unsigned int)s << 16);
}
__device__ __forceinline__ unsigned int pack2bf(float a, float b) {
    return (unsigned int)f2bf(a) | ((unsigned int)f2bf(b) << 16);
}
__device__ __forceinline__ float bf2f_lo(unsigned int u) {
    return __uint_as_float(u << 16);
}
__device__ __forceinline__ float bf2f_hi(unsigned int u) {
    return __uint_as_float(u & 0xFFFF0000u);
}

// 64-lane sum on the VALU pipe via DPP (no LDS-pipe ds_swizzle traffic).
// Cumulative row_shr 1/2/4/8 -> lane{15,31,47,63} hold row-of-16 sums;
// row_bcast:15 merges row pairs; row_bcast:31 merges halves; lane 63 = total;
// readlane(63) broadcasts as a wave-uniform value.
__device__ __forceinline__ float dpp_sum64(float x) {
    x += __int_as_float(__builtin_amdgcn_update_dpp(0, __float_as_int(x), 0x111, 0xf, 0xf, true));
    x += __int_as_float(__builtin_amdgcn_update_dpp(0, __float_as_int(x), 0x112, 0xf, 0xf, true));
    x += __int_as_float(__builtin_amdgcn_update_dpp(0, __float_as_int(x), 0x114, 0xf, 0xf, true));
    x += __int_as_float(__builtin_amdgcn_update_dpp(0, __float_as_int(x), 0x118, 0xf, 0xf, true));
    x += __int_as_float(__builtin_amdgcn_update_dpp(0, __float_as_int(x), 0x142, 0xf, 0xf, true));
    x += __int_as_float(__builtin_amdgcn_update_dpp(0, __float_as_int(x), 0x143, 0xf, 0xf, true));
    return __int_as_float(__builtin_amdgcn_readlane(__float_as_int(x), 63));
}

// ---------------------------------------------------------------------------
// Setup: weight convert into MFMA-FRAGMENT order (z=0..8; z=0 also emits
// lo-plane) and batch lengths (z=9).
// Fragment order: flat = ((tile*NKK + kk)*64 + lane)*8 + j  -> a wave's
// fragment load is base + lane*16B: ONE contiguous 1KB transaction
// (R10-proven: 142 -> 90.5us).
// in-proj (16x16x32): lane = ((k>>3)&3)*16 + (n&15), kk = k>>5, NKK=8.
// win/wout (32x32x16): lane = ((k>>3)&1)*32 + (n&31), kk = k>>4, NKK=16.
// ---------------------------------------------------------------------------
__global__ void k_setup(const float* __restrict__ in_w, const float* __restrict__ win_w,
                        const float* __restrict__ wout_w, const unsigned int* __restrict__ mask_w,
                        unsigned short* __restrict__ wt_in, unsigned short* __restrict__ wt_in_lo,
                        unsigned short* __restrict__ wt_win,
                        unsigned short* __restrict__ wt_wout, int* __restrict__ lengths) {
    int z = blockIdx.z;
    int tid = threadIdx.x;

    if (z == 9) {
        int b = blockIdx.y * 16 + blockIdx.x;
        if (b >= B_) return;
        __shared__ int smode;
        if (tid < 64) {                           // wave 0 only: parallel detect
            unsigned int w0 = mask_w[0];
            unsigned int vi = (tid < 32) ? mask_w[tid * 1024] : 0u;
            unsigned long long anyu8 = __ballot(vi > 1u);
            if (tid == 0) smode = (w0 == 0x3F800000u) ? 2 : (anyu8 ? 1 : 0);
        }
        __syncthreads();
        int mode = smode;
        int s = 0;
        if (mode == 0) {
            const int* m = (const int*)mask_w;
            for (int i = tid; i < S_; i += 256) s += (m[(size_t)b * S_ + i] != 0);
        } else if (mode == 2) {
            const float* m = (const float*)mask_w;
            for (int i = tid; i < S_; i += 256) s += (m[(size_t)b * S_ + i] != 0.0f);
        } else {
            const unsigned char* m = (const unsigned char*)mask_w;
            for (int i = tid; i < S_; i += 256) s += (m[(size_t)b * S_ + i] != 0);
        }
        __shared__ int sm[256];
        sm[tid] = s;
        __syncthreads();
        for (int off = 128; off > 0; off >>= 1) {
            if (tid < off) sm[tid] += sm[tid + off];
            __syncthreads();
        }
        if (tid == 0) lengths[b] = sm[0];
        return;
    }

    const float* src; unsigned short* dst; int N;
    if (z == 0)      { src = in_w;                                   dst = wt_in;                                   N = D_;     }
    else if (z <= 4) { src = win_w  + (size_t)(z - 1) * D_ * 2 * D_; dst = wt_win  + (size_t)(z - 1) * 2 * D_ * D_; N = 2 * D_; }
    else             { src = wout_w + (size_t)(z - 5) * D_ * D_;     dst = wt_wout + (size_t)(z - 5) * D_ * D_;     N = D_;     }
    int bx = blockIdx.x * 32;
    int by = blockIdx.y * 32;
    if (bx >= N) return;
    __shared__ float tile[32][33];
    int tx = tid & 31, ty = tid >> 5;
#pragma unroll
    for (int i = 0; i < 32; i += 8)
        tile[ty + i][tx] = src[(size_t)(by + ty + i) * N + bx + tx];
    __syncthreads();
#pragma unroll
    for (int i = 0; i < 32; i += 8) {
        float f = tile[tx][ty + i];
        unsigned short h = f2bf(f);
        int n = bx + ty + i, k = by + tx;
        if (z == 0) {
            int lane = ((k >> 3) & 3) * 16 + (n & 15);
            size_t idx = ((size_t)((n >> 4) * 8 + (k >> 5)) * 64 + lane) * 8 + (k & 7);
            wt_in[idx] = h;
            wt_in_lo[idx] = f2bf(f - bf2f(h));   // hi/lo split for in-proj
        } else {
            int lane = ((k >> 3) & 1) * 32 + (n & 31);
            size_t idx = ((size_t)((n >> 5) * 16 + (k >> 4)) * 64 + lane) * 8 + (k & 7);
            dst[idx] = h;
        }
    }
}

// ---------------------------------------------------------------------------
// Fully fused network: compress + in-proj + 4 conv blocks + final LN.
// One block per (batch, 16-row segment); 32 rows computed (8 halo/side).
// 512 threads, 70KB LDS. R12 = 86.5us (prefetch + rcp-act).
// R12 PROFILE: MFMA 15%, VALU 30%, ~47us unattributed; perf invariant to
// wave count -> per-CU SHARED LDS PIPE is the serializer (one pipe per CU;
// every __shfl_xor = ds_swizzle on it; ~6.5k LDS instrs/block-pass).
// THIS ROUND: LN reductions moved off the LDS pipe onto the VALU via DPP
// (row_shr 1/2/4/8 + row_bcast 15/31 + readlane) -- removes ~1.6k
// ds_swizzle/block-pass. Everything else frozen from R12.
// ---------------------------------------------------------------------------
__global__ __launch_bounds__(512, 2) void k_fused(
    const float* __restrict__ x, const int* __restrict__ lengths,
    const unsigned short* __restrict__ wt_in, const unsigned short* __restrict__ wt_in_lo,
    const float* __restrict__ in_b,
    const float* __restrict__ ln_g, const float* __restrict__ ln_b,
    const float* __restrict__ dw_w, const float* __restrict__ dw_b,
    const unsigned short* __restrict__ wt_win, const float* __restrict__ win_b,
    const unsigned short* __restrict__ wt_wout, const float* __restrict__ wout_b,
    const float* __restrict__ fn_g, const float* __restrict__ fn_b,
    float* __restrict__ out0, float* __restrict__ out1)
{
    __shared__ unsigned short buf0[BR_][ASTR];   // 19.0 KB: x-lo plane / LN out / act
    __shared__ unsigned short buf1[CR_][ASTR];   // 16.9 KB: x-hi plane / conv out
    __shared__ float h_lds[CR_][HSTR];           // 33.8 KB: resident h (fp32)

    int tid = threadIdx.x;
    int w = tid >> 6, lane = tid & 63;
    int c16 = lane & 15, q = lane >> 4;
    int l31 = lane & 31, lh = lane >> 5;         // 32x32 fragment coords
    int b = blockIdx.x >> 4, seg = blockIdx.x & (SEGS_ - 1);
    int t0 = seg * ORS_;
    // window row r in [0,32) corresponds to t = t0 - 8 + r

    unsigned short (*xlo)[ASTR] = (unsigned short (*)[ASTR])buf0;  // rows 0..31 alias

    int L = lengths[b];

    // ---- compress -> buf1 (hi) + buf0-alias (lo), bf16, 32 rows ----
    {
        int tq = tid & 63, rg = tid >> 6;
        int col = tq * 4;
        float Lf = (float)L;
        float hi = fmaxf(Lf - 1.0f, 0.0f);
        int L1 = max(L - 1, 0);
        const float* xb = x + (size_t)b * S_ * DIN_ + col;
#pragma unroll
        for (int e = 0; e < 4; ++e) {
            int row = rg + e * 8;
            int t = t0 - 8 + row;
            t = min(max(t, 0), T_ - 1);          // out-of-range halo rows: garbage ok, masked at LN
            float src = ((float)t + 0.5f) * (Lf * (1.0f / T_)) - 0.5f;
            src = fminf(fmaxf(src, 0.0f), hi);
            int i0 = (int)floorf(src);
            int i1 = min(i0 + 1, L1);
            float wf = src - (float)i0;
            float4 v0 = *(const float4*)&xb[(size_t)i0 * DIN_];
            float4 v1 = *(const float4*)&xb[(size_t)i1 * DIN_];
            float a0 = (1.0f - wf) * v0.x + wf * v1.x;
            float a1 = (1.0f - wf) * v0.y + wf * v1.y;
            float a2 = (1.0f - wf) * v0.z + wf * v1.z;
            float a3 = (1.0f - wf) * v0.w + wf * v1.w;
            unsigned short h0 = f2bf(a0), h1 = f2bf(a1), h2 = f2bf(a2), h3 = f2bf(a3);
            uint2 oh, ol;
            oh.x = (unsigned int)h0 | ((unsigned int)h1 << 16);
            oh.y = (unsigned int)h2 | ((unsigned int)h3 << 16);
            ol.x = (unsigned int)f2bf(a0 - bf2f(h0)) | ((unsigned int)f2bf(a1 - bf2f(h1)) << 16);
            ol.y = (unsigned int)f2bf(a2 - bf2f(h2)) | ((unsigned int)f2bf(a3 - bf2f(h3)) << 16);
            *(uint2*)&buf1[row][col] = oh;
            *(uint2*)&xlo[row][col] = ol;
        }
    }
    __syncthreads();

    // ---- in-proj GEMM (split precision, fragment-ordered weights) ----
#pragma unroll
    for (int nn = 0; nn < 2; ++nn) {
        int nt = w + nn * 8;
        floatx4 acc[2] = {};
#pragma unroll
        for (int kk = 0; kk < 8; ++kk) {
            size_t fo = ((size_t)(nt * 8 + kk) << 9) + lane * 8;   // (tile*8+kk)*512 + lane*8
            shortx8 bh = *(const shortx8*)(wt_in    + fo);
            shortx8 bl = *(const shortx8*)(wt_in_lo + fo);
#pragma unroll
            for (int mt = 0; mt < 2; ++mt) {
                shortx8 ah = *(const shortx8*)&buf1[mt * 16 + c16][kk * 32 + q * 8];
                shortx8 al = *(const shortx8*)&xlo[mt * 16 + c16][kk * 32 + q * 8];
                acc[mt] = __builtin_amdgcn_mfma_f32_16x16x32_bf16(ah, bh, acc[mt], 0, 0, 0);
                acc[mt] = __builtin_amdgcn_mfma_f32_16x16x32_bf16(al, bh, acc[mt], 0, 0, 0);
                acc[mt] = __builtin_amdgcn_mfma_f32_16x16x32_bf16(ah, bl, acc[mt], 0, 0, 0);
            }
        }
        float obv = in_b[nt * 16 + c16];
#pragma unroll
        for (int mt = 0; mt < 2; ++mt)
#pragma unroll
            for (int r = 0; r < 4; ++r)
                h_lds[mt * 16 + q * 4 + r][nt * 16 + c16] = acc[mt][r] + obv;
    }
    __syncthreads();

    // zero the conv pad rows of buf0 (rows 0,1,34,35; x-lo plane is dead now;
    // disjoint from Stage A's rows 2..33, made visible by the A->B barrier)
    if (tid < 132) {
        ((unsigned int*)buf0[0])[tid] = 0u;
        ((unsigned int*)buf0[1])[tid] = 0u;
        ((unsigned int*)buf0[BR_ - 2])[tid] = 0u;
        ((unsigned int*)buf0[BR_ - 1])[tid] = 0u;
    }

    // ---- 4 conv blocks, h resident in LDS ----
    for (int li = 0; li < NB_; ++li) {
        const float* g_i = ln_g + li * D_;
        const float* b_i = ln_b + li * D_;
        const float* dww = dw_w + (size_t)li * D_ * K_;
        const float* dwb = dw_b + li * D_;
        const unsigned short* ww = wt_win + (size_t)li * 2 * D_ * D_;
        const float* wb = win_b + (size_t)li * 2 * D_;
        const unsigned short* ow = wt_wout + (size_t)li * D_ * D_;
        const float* obp = wout_b + li * D_;

        // prefetch gate win-tile into regs (64 VGPR). Loads issue here and
        // complete across Stage A/B -- register prefetch survives the
        // barrier vmcnt(0) drains (data simply lands early).
        shortx8 Bg[16];
#pragma unroll
        for (int kk = 0; kk < 16; ++kk)
            Bg[kk] = *(const shortx8*)(ww + ((size_t)(w * 16 + kk) << 9) + lane * 8);

        // ---- Stage A: LN h_lds -> buf0 rows 2..33 (bf16), DPP reductions ----
        {
            int c4 = lane * 4;
            float4 g4 = *(const float4*)&g_i[c4];
            float4 b4 = *(const float4*)&b_i[c4];
#pragma unroll
            for (int it = 0; it < 4; ++it) {
                int r = w + it * 8;
                float4 v = *(const float4*)&h_lds[r][c4];
                float s  = dpp_sum64(v.x + v.y + v.z + v.w);
                float ss = dpp_sum64(v.x * v.x + v.y * v.y + v.z * v.z + v.w * v.w);
                float mu = s * (1.0f / D_);
                float rsig = rsqrtf(ss * (1.0f / D_) - mu * mu + EPS_);
                uint2 o;
                o.x = pack2bf((v.x - mu) * rsig * g4.x + b4.x,
                              (v.y - mu) * rsig * g4.y + b4.y);
                o.y = pack2bf((v.z - mu) * rsig * g4.z + b4.z,
                              (v.w - mu) * rsig * g4.w + b4.w);
                int t = t0 - 8 + r;
                if (t < 0 || t >= T_) { o.x = 0; o.y = 0; }   // zero-padded conv boundary
                *(uint2*)&buf0[r + 2][c4] = o;
            }
        }
        __syncthreads();

        // ---- Stage B: depthwise conv buf0 -> buf1 (32 rows) ----
        {
            int tq = tid & 63, rg = tid >> 6;
            int col = tq * 4;
            float4 wk[K_];
#pragma unroll
            for (int k = 0; k < K_; ++k) {
                wk[k].x = dww[(col + 0) * K_ + k];
                wk[k].y = dww[(col + 1) * K_ + k];
                wk[k].z = dww[(col + 2) * K_ + k];
                wk[k].w = dww[(col + 3) * K_ + k];
            }
            float4 cb4 = *(const float4*)&dwb[col];
#pragma unroll
            for (int e = 0; e < 4; ++e) {
                int rr = rg + e * 8;
                float4 acc = cb4;
#pragma unroll
                for (int k = 0; k < K_; ++k) {
                    uint2 u = *(const uint2*)&buf0[rr + k][col];
                    acc.x += bf2f_lo(u.x) * wk[k].x;
                    acc.y += bf2f_hi(u.x) * wk[k].y;
                    acc.z += bf2f_lo(u.y) * wk[k].z;
                    acc.w += bf2f_hi(u.y) * wk[k].w;
                }
                uint2 o;
                o.x = pack2bf(acc.x, acc.y);
                o.y = pack2bf(acc.z, acc.w);
                *(uint2*)&buf1[rr][col] = o;
            }
        }
        __syncthreads();

        // ---- Stage C: win GEMM (32x512) via 32x32x16 MFMA + fused act ----
        // Gate weights from prefetched Bg; val weights stream inline (hidden
        // under the MFMA chain). One A-read per kk feeds both tiles.
        {
            floatx16 accG = {}, accV = {};
#pragma unroll
            for (int kk = 0; kk < 16; ++kk) {
                shortx8 a  = *(const shortx8*)&buf1[l31][kk * 16 + lh * 8];
                shortx8 bv = *(const shortx8*)(ww + ((size_t)((8 + w) * 16 + kk) << 9) + lane * 8);
                accG = __builtin_amdgcn_mfma_f32_32x32x16_bf16(a, Bg[kk], accG, 0, 0, 0);
                accV = __builtin_amdgcn_mfma_f32_32x32x16_bf16(a, bv, accV, 0, 0, 0);
            }
            // prefetch first half of wout tile (32 VGPR) under the act epilogue
            shortx8 Bo[8];
#pragma unroll
            for (int kk = 0; kk < 8; ++kk)
                Bo[kk] = *(const shortx8*)(ow + ((size_t)(w * 16 + kk) << 9) + lane * 8);
            float bg0 = wb[w * 32 + l31];
            float bv0 = wb[256 + w * 32 + l31];
#pragma unroll
            for (int r = 0; r < 16; ++r) {
                int row = (r & 3) + 8 * (r >> 2) + 4 * lh;
                float gate = accG[r] + bg0;
                float val  = accV[r] + bv0;
                float u = 1.5957691216f * (val + 0.044715f * val * val * val);
                float den = (1.0f + __expf(-gate)) * (1.0f + __expf(-u));
                buf0[2 + row][w * 32 + l31] = f2bf(val * __builtin_amdgcn_rcpf(den));
            }
            __syncthreads();

            // ---- Stage D: wout GEMM (32x256) via 32x32x16 + residual ----
            floatx16 acc = {};
#pragma unroll
            for (int kk = 0; kk < 8; ++kk) {
                shortx8 a = *(const shortx8*)&buf0[2 + l31][kk * 16 + lh * 8];
                acc = __builtin_amdgcn_mfma_f32_32x32x16_bf16(a, Bo[kk], acc, 0, 0, 0);
            }
#pragma unroll
            for (int kk = 8; kk < 16; ++kk) {
                shortx8 a  = *(const shortx8*)&buf0[2 + l31][kk * 16 + lh * 8];
                shortx8 bo = *(const shortx8*)(ow + ((size_t)(w * 16 + kk) << 9) + lane * 8);
                acc = __builtin_amdgcn_mfma_f32_32x32x16_bf16(a, bo, acc, 0, 0, 0);
            }
            float bb = obp[w * 32 + l31];
#pragma unroll
            for (int r = 0; r < 16; ++r) {
                int row = (r & 3) + 8 * (r >> 2) + 4 * lh;
                int col = w * 32 + l31;
                h_lds[row][col] = h_lds[row][col] + acc[r] + bb;
            }
        }
        __syncthreads();
    }

    // ---- final LN on owned rows (8..23) -> out0; comp_mask -> out1 ----
    {
        int c4 = lane * 4;
        float4 g4 = *(const float4*)&fn_g[c4];
        float4 b4 = *(const float4*)&fn_b[c4];
#pragma unroll
        for (int it = 0; it < 2; ++it) {
            int r = 8 + w + it * 8;
            float4 v = *(const float4*)&h_lds[r][c4];
            float s  = dpp_sum64(v.x + v.y + v.z + v.w);
            float ss = dpp_sum64(v.x * v.x + v.y * v.y + v.z * v.z + v.w * v.w);
            float mu = s * (1.0f / D_);
            float rsig = rsqrtf(ss * (1.0f / D_) - mu * mu + EPS_);
            float4 o;
            o.x = (v.x - mu) * rsig * g4.x + b4.x;
            o.y = (v.y - mu) * rsig * g4.y + b4.y;
            o.z = (v.z - mu) * rsig * g4.z + b4.z;
            o.w = (v.w - mu) * rsig * g4.w + b4.w;
            *(float4*)&out0[((size_t)b * T_ + t0 + r - 8) * D_ + c4] = o;
        }
        if (tid < ORS_) out1[(size_t)b * T_ + t0 + tid] = 1.0f;
    }
}

// ---------------------------------------------------------------------------
extern "C" void kernel_launch(void* const* d_in, const int* in_sizes, int n_in,
                              void* d_out, int out_size, void* d_ws, size_t ws_size,
                              hipStream_t stream) {
    const float* x      = (const float*)d_in[0];
    const unsigned int* mask_w = (const unsigned int*)d_in[1];
    const float* in_w   = (const float*)d_in[2];
    const float* in_b   = (const float*)d_in[3];
    const float* ln_g   = (const float*)d_in[4];
    const float* ln_b   = (const float*)d_in[5];
    const float* dw_w   = (const float*)d_in[6];
    const float* dw_b   = (const float*)d_in[7];
    const float* win_w  = (const float*)d_in[8];
    const float* win_b  = (const float*)d_in[9];
    const float* wout_w = (const float*)d_in[10];
    const float* wout_b = (const float*)d_in[11];
    const float* fn_g   = (const float*)d_in[12];
    const float* fn_b   = (const float*)d_in[13];

    char* w8 = (char*)d_ws;
    unsigned short* wt_in   = (unsigned short*)w8;                 // 128 KB
    unsigned short* wt_win  = wt_in  + (size_t)D_ * DIN_;          // 1 MB
    unsigned short* wt_wout = wt_win + (size_t)NB_ * 2 * D_ * D_;  // 512 KB
    int* lengths = (int*)(w8 + (2u << 20));                        // 128 B
    unsigned short* wt_in_lo = (unsigned short*)(w8 + (3u << 20)); // 128 KB

    float* out0 = (float*)d_out;
    float* out1 = out0 + (size_t)ROWS_ * D_;

    k_setup<<<dim3(16, 8, 10), 256, 0, stream>>>(in_w, win_w, wout_w, mask_w,
                                                 wt_in, wt_in_lo, wt_win, wt_wout, lengths);
    k_fused<<<B_ * SEGS_, 512, 0, stream>>>(x, lengths, wt_in, wt_in_lo, in_b,
                                            ln_g, ln_b, dw_w, dw_b,
                                            wt_win, win_b, wt_wout, wout_b,
                                            fn_g, fn_b, out0, out1);
}